// Round 5
// baseline (94.171 us; speedup 1.0000x reference)
//
#include <hip/hip_runtime.h>

// LightweightConv1d: x (T,B,C) f32, weight (H,1,K) f32 (softmax over K), bias (C) f32
// out[t,b,c] = bias[c] + sum_k softmax(w[h])[k] * x[t-P+k, b, c],  h = c / (C/H)
//
// Streaming multi-accumulator form: each thread owns TT=32 consecutive outputs of
// one (b,c) column and streams the 62 needed inputs once each, FMA-ing into the
// accumulators. Accumulators are partial sums -> cannot be rematerialized from
// memory, so the allocator MUST keep them in VGPRs (defeats the remat pathology
// that plagued the sliding-window versions: VGPR=24/32, serialized reloads).
#define T_DIM 2048
#define B_DIM 32
#define C_DIM 512
#define H_DIM 16
#define K_DIM 31
#define P_PAD 15
#define TT 32                      // outputs (accumulators) per thread
#define JN (TT + K_DIM - 1)        // 62 streamed inputs per thread
#define NCOL (B_DIM * C_DIM)       // 16384 floats between consecutive t

__global__ __launch_bounds__(256, 8)
void lwconv_kernel(const float* __restrict__ x, const float* __restrict__ weight,
                   const float* __restrict__ bias, float* __restrict__ out)
{
    const int wid  = __builtin_amdgcn_readfirstlane((int)(threadIdx.x >> 6));
    const int lane = threadIdx.x & 63;
    const int gw   = blockIdx.x * 4 + wid;        // global wave id (scalar)
    const int h    = gw & (H_DIM - 1);            // head (wave-uniform)
    const int bp   = (gw >> 4) & 15;              // batch pair (uniform)
    const int tblk = gw >> 8;                     // t-block 0..63 (uniform)
    const int c    = (h << 5) | (lane & 31);      // 32 channels of head h
    const int b    = (bp << 1) | (lane >> 5);     // 2 batches per wave
    const int col  = b * C_DIM + c;               // two 128B segments per wave

    // per-lane softmax of the head's 31 weights (uniform inputs), then -> SGPR
    float w[K_DIM];
    float m = -3.4e38f;
    #pragma unroll
    for (int k = 0; k < K_DIM; ++k) { w[k] = weight[h * K_DIM + k]; m = fmaxf(m, w[k]); }
    float s = 0.f;
    #pragma unroll
    for (int k = 0; k < K_DIM; ++k) { w[k] = __expf(w[k] - m); s += w[k]; }
    const float inv = 1.f / s;
    unsigned int ws[K_DIM];
    #pragma unroll
    for (int k = 0; k < K_DIM; ++k)
        ws[k] = __builtin_amdgcn_readfirstlane(__float_as_uint(w[k] * inv));

    const float bv = bias[c];
    const int tb = tblk * TT;                     // first output t of this thread
    const float* xp = x + col;
    float*       op = out + col;

    float acc[TT];
    #pragma unroll
    for (int i = 0; i < TT; ++i) acc[i] = bv;

    // Stream 62 inputs; each feeds 1..31 accumulators. Loads are unconditional
    // (clamped address) and masked by a uniform scalar factor -> freely
    // hoistable/pipelined by the scheduler.
    #pragma unroll
    for (int j = 0; j < JN; ++j) {
        const int t  = tb - P_PAD + j;            // block-uniform
        int tc = t < 0 ? 0 : (t >= T_DIM ? T_DIM - 1 : t);
        float v = xp[(size_t)tc * NCOL];
        if (t < 0 || t >= T_DIM) v = 0.f;         // uniform cndmask/cselect
        const int ilo = (j - (K_DIM - 1)) > 0 ? (j - (K_DIM - 1)) : 0;
        const int ihi = j < (TT - 1) ? j : (TT - 1);
        #pragma unroll
        for (int i = ilo; i <= ihi; ++i)
            acc[i] = fmaf(__uint_as_float(ws[j - i]), v, acc[i]);
    }

    #pragma unroll
    for (int i = 0; i < TT; ++i)
        op[(size_t)(tb + i) * NCOL] = acc[i];
}

extern "C" void kernel_launch(void* const* d_in, const int* in_sizes, int n_in,
                              void* d_out, int out_size, void* d_ws, size_t ws_size,
                              hipStream_t stream) {
    const float* x      = (const float*)d_in[0];
    const float* weight = (const float*)d_in[1];
    const float* bias   = (const float*)d_in[2];
    float* out = (float*)d_out;
    // waves = H(16) * batch-pairs(16) * t-blocks(64) = 16384 -> 4096 blocks of 4 waves.
    // Halo-sharing neighbors (same columns, tblk +/- 1) are bid +/- 64 -> same XCD
    // under the default bid%8 round-robin; no swizzle needed.
    dim3 grid(H_DIM * 16 * (T_DIM / TT) / 4);
    dim3 block(256);
    lwconv_kernel<<<grid, block, 0, stream>>>(x, weight, bias, out);
}

// Round 6
// 52.424 us; speedup vs baseline: 1.7963x; 1.7963x over previous
//
#include <hip/hip_runtime.h>

// LightweightConv1d: x (T,B,C) f32, weight (H,1,K) f32 (softmax over K), bias (C) f32
// out[t,b,c] = bias[c] + sum_k softmax(w[h])[k] * x[t-P+k, b, c],  h = c / (C/H)
//
// Streaming multi-accumulator form: each thread owns TT=32 consecutive outputs of
// one (b,c) column and streams the 62 needed inputs once each, FMA-ing into the
// accumulators (partial sums -> not rematerializable). Register working set:
// 32 accs + ~60 in-flight loads + addressing ~= 105 VGPR, so the budget must be
// 128 (launch_bounds min-waves=4). R5 proved 64-VGPR cap => accumulator spill
// (WRITE 213MB); R3/R4 proved window-carry => remat. This config has neither.
#define T_DIM 2048
#define B_DIM 32
#define C_DIM 512
#define H_DIM 16
#define K_DIM 31
#define P_PAD 15
#define TT 32                      // outputs (accumulators) per thread
#define JN (TT + K_DIM - 1)        // 62 streamed inputs per thread
#define NCOL (B_DIM * C_DIM)       // 16384 floats between consecutive t

__global__ __launch_bounds__(256, 4)
void lwconv_kernel(const float* __restrict__ x, const float* __restrict__ weight,
                   const float* __restrict__ bias, float* __restrict__ out)
{
    const int wid  = __builtin_amdgcn_readfirstlane((int)(threadIdx.x >> 6));
    const int lane = threadIdx.x & 63;
    const int gw   = blockIdx.x * 4 + wid;        // global wave id (scalar)
    const int h    = gw & (H_DIM - 1);            // head (wave-uniform)
    const int bp   = (gw >> 4) & 15;              // batch pair (uniform)
    const int tblk = gw >> 8;                     // t-block 0..63 (uniform)
    const int c    = (h << 5) | (lane & 31);      // 32 channels of head h
    const int b    = (bp << 1) | (lane >> 5);     // 2 batches per wave
    const int col  = b * C_DIM + c;               // two 128B segments per wave

    // per-lane softmax of the head's 31 weights (uniform inputs), then -> SGPR
    float w[K_DIM];
    float m = -3.4e38f;
    #pragma unroll
    for (int k = 0; k < K_DIM; ++k) { w[k] = weight[h * K_DIM + k]; m = fmaxf(m, w[k]); }
    float s = 0.f;
    #pragma unroll
    for (int k = 0; k < K_DIM; ++k) { w[k] = __expf(w[k] - m); s += w[k]; }
    const float inv = 1.f / s;
    unsigned int ws[K_DIM];
    #pragma unroll
    for (int k = 0; k < K_DIM; ++k)
        ws[k] = __builtin_amdgcn_readfirstlane(__float_as_uint(w[k] * inv));

    const float bv = bias[c];
    const int tb = tblk * TT;                     // first output t of this thread
    const float* xp = x + col;
    float*       op = out + col;

    float acc[TT];
    #pragma unroll
    for (int i = 0; i < TT; ++i) acc[i] = bv;

    // Stream 62 inputs; each feeds 1..31 accumulators. Loads are unconditional
    // (clamped address) and zeroed by a block-uniform predicate -> the whole
    // 62-load stream is hoistable and pipelines deeply within the 128-reg budget.
    #pragma unroll
    for (int j = 0; j < JN; ++j) {
        const int t  = tb - P_PAD + j;            // block-uniform
        int tc = t < 0 ? 0 : (t >= T_DIM ? T_DIM - 1 : t);
        float v = xp[(size_t)tc * NCOL];
        if (t < 0 || t >= T_DIM) v = 0.f;         // uniform cndmask/cselect
        const int ilo = (j - (K_DIM - 1)) > 0 ? (j - (K_DIM - 1)) : 0;
        const int ihi = j < (TT - 1) ? j : (TT - 1);
        #pragma unroll
        for (int i = ilo; i <= ihi; ++i)
            acc[i] = fmaf(__uint_as_float(ws[j - i]), v, acc[i]);
    }

    #pragma unroll
    for (int i = 0; i < TT; ++i)
        op[(size_t)(tb + i) * NCOL] = acc[i];
}

extern "C" void kernel_launch(void* const* d_in, const int* in_sizes, int n_in,
                              void* d_out, int out_size, void* d_ws, size_t ws_size,
                              hipStream_t stream) {
    const float* x      = (const float*)d_in[0];
    const float* weight = (const float*)d_in[1];
    const float* bias   = (const float*)d_in[2];
    float* out = (float*)d_out;
    // waves = H(16) * batch-pairs(16) * t-blocks(64) = 16384 -> 4096 blocks of 4 waves.
    // Halo-sharing neighbors (same columns, tblk +/- 1) are bid +/- 64 -> same XCD
    // under the default bid%8 round-robin; no swizzle needed.
    dim3 grid(H_DIM * 16 * (T_DIM / TT) / 4);
    dim3 block(256);
    lwconv_kernel<<<grid, block, 0, stream>>>(x, weight, bias, out);
}